// Round 4
// baseline (238.843 us; speedup 1.0000x reference)
//
#include <hip/hip_runtime.h>
#include <hip/hip_bf16.h>
#include <math.h>

#define TT 2048
#define CC 1024
#define C3 3072
#define MM 8192   // B*T

typedef __attribute__((ext_vector_type(8))) short short8;
typedef __attribute__((ext_vector_type(4))) float f32x4;

__device__ __forceinline__ short bf16b(float x) {
  __hip_bfloat16 h = __float2bfloat16(x);
  return *reinterpret_cast<short*>(&h);
}

__device__ __forceinline__ unsigned cvtpk(float lo, float hi) {
  unsigned r;
  asm("v_cvt_pk_bf16_f32 %0, %1, %2" : "=v"(r) : "v"(lo), "v"(hi));
  return r;
}

__device__ __forceinline__ void gload16(const void* g, void* l) {
  __builtin_amdgcn_global_load_lds(
      (const __attribute__((address_space(1))) unsigned int*)g,
      (__attribute__((address_space(3))) unsigned int*)l, 16, 0, 0);
}

// ---------------------------------------------------------------------------
// fp32 -> bf16 bits, 8 elems/thread
// ---------------------------------------------------------------------------
__global__ __launch_bounds__(256) void cvt_x(const float* __restrict__ in,
                                             short* __restrict__ out, int n) {
  int i = (blockIdx.x * 256 + threadIdx.x) * 8;
  if (i >= n) return;
  float4 a = *reinterpret_cast<const float4*>(in + i);
  float4 b = *reinterpret_cast<const float4*>(in + i + 4);
  short8 r;
  r[0] = bf16b(a.x); r[1] = bf16b(a.y); r[2] = bf16b(a.z); r[3] = bf16b(a.w);
  r[4] = bf16b(b.x); r[5] = bf16b(b.y); r[6] = bf16b(b.z); r[7] = bf16b(b.w);
  *reinterpret_cast<short8*>(out + i) = r;
}

// ---------------------------------------------------------------------------
// transpose + convert: in [R][Cc] fp32 -> out [Cc][R] bf16
// ---------------------------------------------------------------------------
__global__ __launch_bounds__(256) void cvt_t(const float* __restrict__ in,
                                             short* __restrict__ out, int R, int Cc) {
  __shared__ float t[32][33];
  int c0 = blockIdx.x * 32, r0 = blockIdx.y * 32;
  int tx = threadIdx.x & 31, ty = threadIdx.x >> 5;
#pragma unroll
  for (int i = 0; i < 4; ++i)
    t[ty + i * 8][tx] = in[(size_t)(r0 + ty + i * 8) * Cc + c0 + tx];
  __syncthreads();
#pragma unroll
  for (int i = 0; i < 4; ++i)
    out[(size_t)(c0 + ty + i * 8) * R + r0 + tx] = bf16b(t[tx][ty + i * 8]);
}

// ---------------------------------------------------------------------------
// bf16 MFMA GEMM: C[M,N] = A[M,K] * Bt[N,K]^T.  128x128 tile, BK=32,
// 256 threads = 4 waves (2x2), 4x4 16x16 frags/wave, global_load_lds staging.
// MODE 0: fp32 out.  MODE 2: qkv mode — cols<2048 -> bf16 qkv; cols>=2048
// (the V third) scatter to key-permuted vT[bh*64+d][t'] (replaces vtrans).
// ---------------------------------------------------------------------------
template <int MODE>
__global__ __launch_bounds__(256) void gemm_bt(const short* __restrict__ A,
                                               const short* __restrict__ Bt,
                                               void* __restrict__ Cout,
                                               short* __restrict__ vT,
                                               int M, int N, int K) {
  __shared__ __align__(16) short As[128 * 32];
  __shared__ __align__(16) short Bs[128 * 32];
  const int tid = threadIdx.x, lane = tid & 63, w = tid >> 6;
  const int g = lane >> 4, cw = lane & 15;
  const int m0 = blockIdx.y * 128, n0 = blockIdx.x * 128;
  const int wr = (w >> 1) * 64, wc = (w & 1) * 64;

  f32x4 acc[4][4];
#pragma unroll
  for (int i = 0; i < 4; ++i)
#pragma unroll
    for (int j = 0; j < 4; ++j) acc[i][j] = (f32x4){0.f, 0.f, 0.f, 0.f};

  const int srow = w * 16 + (lane >> 2);  // + u*64
  const int scol = (lane & 3) * 8;        // k elements

  for (int k0 = 0; k0 < K; k0 += 32) {
    __syncthreads();
#pragma unroll
    for (int u = 0; u < 2; ++u) {
      gload16(A + (size_t)(m0 + srow + u * 64) * K + k0 + scol,
              (char*)As + u * 4096 + w * 1024);
      gload16(Bt + (size_t)(n0 + srow + u * 64) * K + k0 + scol,
              (char*)Bs + u * 4096 + w * 1024);
    }
    __syncthreads();
    short8 af[4], bf[4];
#pragma unroll
    for (int mt = 0; mt < 4; ++mt)
      af[mt] = *reinterpret_cast<const short8*>(&As[(wr + mt * 16 + cw) * 32 + g * 8]);
#pragma unroll
    for (int nt = 0; nt < 4; ++nt)
      bf[nt] = *reinterpret_cast<const short8*>(&Bs[(wc + nt * 16 + cw) * 32 + g * 8]);
#pragma unroll
    for (int mt = 0; mt < 4; ++mt)
#pragma unroll
      for (int nt = 0; nt < 4; ++nt)
        acc[mt][nt] = __builtin_amdgcn_mfma_f32_16x16x32_bf16(af[mt], bf[nt], acc[mt][nt], 0, 0, 0);
  }

#pragma unroll
  for (int mt = 0; mt < 4; ++mt)
#pragma unroll
    for (int nt = 0; nt < 4; ++nt)
#pragma unroll
      for (int j = 0; j < 4; ++j) {
        const int row = m0 + wr + mt * 16 + g * 4 + j;
        const int col = n0 + wc + nt * 16 + cw;
        if (MODE == 0) {
          ((float*)Cout)[(size_t)row * N + col] = acc[mt][nt][j];
        } else {
          if (col < 2048) {
            ((short*)Cout)[(size_t)row * N + col] = bf16b(acc[mt][nt][j]);
          } else {
            // V third -> key-permuted transposed layout (was vtrans kernel)
            const int cv = col - 2048;
            const int h = cv >> 6, d = cv & 63;
            const int b = row >> 11, t = row & 2047;
            const int l5 = t & 31;
            const int tp = (t & ~31) | ((l5 & 8) << 1) | ((l5 & 4) << 1) |
                           ((l5 & 16) >> 2) | (l5 & 3);
            vT[(size_t)((b * 16 + h) * 64 + d) * TT + tp] = bf16b(acc[mt][nt][j]);
          }
        }
      }
}

// ---------------------------------------------------------------------------
// Flash attention, swapped-operand MFMA.
// Block = 4 waves; wave w owns 32 q rows; q-tile 128; KV-tile 64.
// Causal pairing: blockIdx.x=i handles q-tiles {i, 15-i} (34 KV-tiles total).
// Swapped QK^T (lane q = cw) -> softmax local; P packs into PV A-frags via
// cvt_pk (zero shuffles; vT key-permuted).  Interior tiles skip masking
// (wave-uniform); defer-max skips the O-rescale broadcast chain; exp2 domain.
// ---------------------------------------------------------------------------
__global__ __launch_bounds__(256) void attn_mfma(const short* __restrict__ qkv,
                                                 const short* __restrict__ vT,
                                                 const int* __restrict__ amask,
                                                 short* __restrict__ y) {
  __shared__ __align__(16) char Ks[8192];   // [key][128B], swizzled
  __shared__ __align__(16) char Vs[8192];   // [d][128B perm-keys], swizzled
  const int tid = threadIdx.x, lane = tid & 63, w = tid >> 6;
  const int g = lane >> 4, cw = lane & 15;
  const int bh = blockIdx.y, b = bh >> 4, h = bh & 15;
  const int xorm = (cw & 7) << 4;
  const int srow = w * 8 + (lane >> 3);                    // staging row (+u*32)
  const int scb = (((lane & 7) ^ (lane >> 3)) << 4);       // pre-swizzled src col byte
  const float SC = 0.1803368801f;                          // log2(e)/8

#pragma unroll 1
  for (int part = 0; part < 2; ++part) {
    const int qt = part ? 15 - (int)blockIdx.x : (int)blockIdx.x;
    const int q0 = qt * 128;
    const int qw = q0 + w * 32;

    // Q fragments (B-operand: lane holds Q[q = qw+mt*16+cw][d contiguous])
    short8 qf[2][2];
#pragma unroll
    for (int mt = 0; mt < 2; ++mt)
#pragma unroll
      for (int ks = 0; ks < 2; ++ks)
        qf[mt][ks] = *reinterpret_cast<const short8*>(
            &qkv[(size_t)(b * TT + qw + mt * 16 + cw) * C3 + h * 64 + ks * 32 + g * 8]);

    f32x4 o[2][4];
#pragma unroll
    for (int mt = 0; mt < 2; ++mt)
#pragma unroll
      for (int nd = 0; nd < 4; ++nd) o[mt][nd] = (f32x4){0.f, 0.f, 0.f, 0.f};
    float mx[2] = {-1e30f, -1e30f}, ls[2] = {0.f, 0.f};

    const char* ksrc = (const char*)qkv + ((size_t)(b * TT + srow) * C3 + CC + h * 64) * 2 + scb;
    const char* vsrc = (const char*)vT + ((size_t)(bh * 64 + srow) * TT) * 2 + scb;
    const int* amp = amask + b * TT + lane;

    const int ntiles = 2 * qt + 2;
    for (int t = 0; t < ntiles; ++t) {
      __syncthreads();
#pragma unroll
      for (int u = 0; u < 2; ++u) {
        gload16(ksrc + (size_t)u * 32 * C3 * 2, Ks + u * 4096 + w * 1024 + lane * 16);
        gload16(vsrc + (size_t)u * 32 * TT * 2, Vs + u * 4096 + w * 1024 + lane * 16);
      }
      const unsigned long long kbits = __ballot(amp[0] != 0);
      ksrc += (size_t)64 * C3 * 2;
      vsrc += 128;
      amp += 64;
      __syncthreads();

      if (t * 64 > qw + 31) continue;   // tile entirely above this wave's rows

      // ---- S^T = K Q^T : lane holds q = cw, keys nt*16 + g*4 + j ----
      f32x4 s[2][4];
#pragma unroll
      for (int nt = 0; nt < 4; ++nt) {
        const int r = nt * 16 + cw;
#pragma unroll
        for (int ks = 0; ks < 2; ++ks) {
          short8 kf = *reinterpret_cast<const short8*>(
              Ks + r * 128 + ((ks * 64 + g * 16) ^ xorm));
          if (ks == 0) {
            f32x4 z = (f32x4){0.f, 0.f, 0.f, 0.f};
            s[0][nt] = __builtin_amdgcn_mfma_f32_16x16x32_bf16(kf, qf[0][0], z, 0, 0, 0);
            s[1][nt] = __builtin_amdgcn_mfma_f32_16x16x32_bf16(kf, qf[1][0], z, 0, 0, 0);
          } else {
            s[0][nt] = __builtin_amdgcn_mfma_f32_16x16x32_bf16(kf, qf[0][1], s[0][nt], 0, 0, 0);
            s[1][nt] = __builtin_amdgcn_mfma_f32_16x16x32_bf16(kf, qf[1][1], s[1][nt], 0, 0, 0);
          }
        }
      }

      // ---- scale (exp2 domain); mask only on boundary tiles ----
      const bool needMask = (t * 64 + 63 > qw) || (kbits != ~0ULL);
#pragma unroll
      for (int nt = 0; nt < 4; ++nt)
#pragma unroll
        for (int j = 0; j < 4; ++j) {
#pragma unroll
          for (int mt = 0; mt < 2; ++mt) s[mt][nt][j] *= SC;
        }
      if (needMask) {
#pragma unroll
        for (int nt = 0; nt < 4; ++nt)
#pragma unroll
          for (int j = 0; j < 4; ++j) {
            const int kh = nt * 16 + g * 4 + j;
            const int key = t * 64 + kh;
            const bool mok = (kbits >> kh) & 1;
#pragma unroll
            for (int mt = 0; mt < 2; ++mt) {
              const int q = qw + mt * 16 + cw;
              if (!(mok && key <= q)) s[mt][nt][j] = -1e30f;
            }
          }
      }

      // ---- online softmax with defer-max + pack P into A-frags ----
      short8 pa[2][2];
#pragma unroll
      for (int mt = 0; mt < 2; ++mt) {
        float vmax = s[mt][0][0];
#pragma unroll
        for (int nt = 0; nt < 4; ++nt)
#pragma unroll
          for (int j = 0; j < 4; ++j) vmax = fmaxf(vmax, s[mt][nt][j]);
        vmax = fmaxf(vmax, __shfl_xor(vmax, 16));
        vmax = fmaxf(vmax, __shfl_xor(vmax, 32));
        if (!__all(vmax <= mx[mt] + 12.f)) {
          const float mn = fmaxf(mx[mt], vmax);
          const float al = exp2f(mx[mt] - mn);
          mx[mt] = mn;
          ls[mt] *= al;
#pragma unroll
          for (int j = 0; j < 4; ++j) {
            const float aj = __shfl(al, (lane & 48) | (g * 4 + j));
#pragma unroll
            for (int nd = 0; nd < 4; ++nd) o[mt][nd][j] *= aj;
          }
        }
        float rs = 0.f;
#pragma unroll
        for (int nt = 0; nt < 4; ++nt)
#pragma unroll
          for (int j = 0; j < 4; ++j) {
            const float p = exp2f(s[mt][nt][j] - mx[mt]);
            s[mt][nt][j] = p;
            rs += p;
          }
        rs += __shfl_xor(rs, 16);
        rs += __shfl_xor(rs, 32);
        ls[mt] += rs;
        union { unsigned u[4]; short8 s8; } pc;
#pragma unroll
        for (int ks2 = 0; ks2 < 2; ++ks2) {
          pc.u[0] = cvtpk(s[mt][2 * ks2][0], s[mt][2 * ks2][1]);
          pc.u[1] = cvtpk(s[mt][2 * ks2][2], s[mt][2 * ks2][3]);
          pc.u[2] = cvtpk(s[mt][2 * ks2 + 1][0], s[mt][2 * ks2 + 1][1]);
          pc.u[3] = cvtpk(s[mt][2 * ks2 + 1][2], s[mt][2 * ks2 + 1][3]);
          pa[mt][ks2] = pc.s8;
        }
      }

      // ---- O += P V  (B-frags from permuted Vs) ----
#pragma unroll
      for (int ks2 = 0; ks2 < 2; ++ks2)
#pragma unroll
        for (int nd = 0; nd < 4; ++nd) {
          const int r = nd * 16 + cw;
          short8 vf = *reinterpret_cast<const short8*>(
              Vs + r * 128 + ((ks2 * 64 + g * 16) ^ xorm));
          o[0][nd] = __builtin_amdgcn_mfma_f32_16x16x32_bf16(pa[0][ks2], vf, o[0][nd], 0, 0, 0);
          o[1][nd] = __builtin_amdgcn_mfma_f32_16x16x32_bf16(pa[1][ks2], vf, o[1][nd], 0, 0, 0);
        }
    }

    // ---- epilogue: y = O / l ----
#pragma unroll
    for (int mt = 0; mt < 2; ++mt)
#pragma unroll
      for (int j = 0; j < 4; ++j) {
        const float lj = __shfl(ls[mt], (lane & 48) | (g * 4 + j));
        const float inv = 1.f / lj;
        const int q = qw + mt * 16 + g * 4 + j;
#pragma unroll
        for (int nd = 0; nd < 4; ++nd)
          y[(size_t)(b * TT + q) * CC + h * 64 + nd * 16 + cw] = bf16b(o[mt][nd][j] * inv);
      }
  }
}

// ---------------------------------------------------------------------------
extern "C" void kernel_launch(void* const* d_in, const int* in_sizes, int n_in,
                              void* d_out, int out_size, void* d_ws, size_t ws_size,
                              hipStream_t stream) {
  const float* x      = (const float*)d_in[0];
  const int*   amask  = (const int*)d_in[1];
  const float* W_attn = (const float*)d_in[2];
  const float* W_proj = (const float*)d_in[3];

  char* ws = (char*)d_ws;
  short* xb  = (short*)(ws);                    // [8192][1024] bf16   16.8 MB
  short* Wta = (short*)(ws + 16777216);         // [3072][1024] bf16    6.3 MB
  short* Wtp = (short*)(ws + 23068672);         // [1024][1024] bf16    2.1 MB
  short* qkv = (short*)(ws + 25165824);         // [8192][3072] bf16   50.3 MB
  short* y   = (short*)(ws + 75497472);         // [8192][1024] bf16   16.8 MB
  short* vT  = (short*)(ws + 92274688);         // [64bh][64d][2048t]  16.8 MB

  cvt_x<<<MM * CC / (256 * 8), 256, 0, stream>>>(x, xb, MM * CC);
  {
    dim3 g(C3 / 32, CC / 32);
    cvt_t<<<g, 256, 0, stream>>>(W_attn, Wta, CC, C3);
  }
  {
    dim3 g(CC / 32, CC / 32);
    cvt_t<<<g, 256, 0, stream>>>(W_proj, Wtp, CC, CC);
  }
  {
    dim3 g(C3 / 128, MM / 128);
    gemm_bt<2><<<g, 256, 0, stream>>>(xb, Wta, qkv, vT, MM, C3, CC);
  }
  {
    dim3 g(8, 64);
    attn_mfma<<<g, 256, 0, stream>>>(qkv, vT, amask, y);
  }
  {
    dim3 g(CC / 128, MM / 128);
    gemm_bt<0><<<g, 256, 0, stream>>>(y, Wtp, (void*)d_out, nullptr, MM, CC, CC);
  }
}

// Round 5
// 211.644 us; speedup vs baseline: 1.1285x; 1.1285x over previous
//
#include <hip/hip_runtime.h>
#include <hip/hip_bf16.h>
#include <math.h>

#define TT 2048
#define CC 1024
#define C3 3072
#define MM 8192   // B*T

typedef __attribute__((ext_vector_type(8))) short short8;
typedef __attribute__((ext_vector_type(4))) float f32x4;

__device__ __forceinline__ short bf16b(float x) {
  __hip_bfloat16 h = __float2bfloat16(x);
  return *reinterpret_cast<short*>(&h);
}

__device__ __forceinline__ unsigned cvtpk(float lo, float hi) {
  unsigned r;
  asm("v_cvt_pk_bf16_f32 %0, %1, %2" : "=v"(r) : "v"(lo), "v"(hi));
  return r;
}

__device__ __forceinline__ void gload16(const void* g, void* l) {
  __builtin_amdgcn_global_load_lds(
      (const __attribute__((address_space(1))) unsigned int*)g,
      (__attribute__((address_space(3))) unsigned int*)l, 16, 0, 0);
}

// ---------------------------------------------------------------------------
// fp32 -> bf16 bits, 8 elems/thread
// ---------------------------------------------------------------------------
__global__ __launch_bounds__(256) void cvt_x(const float* __restrict__ in,
                                             short* __restrict__ out, int n) {
  int i = (blockIdx.x * 256 + threadIdx.x) * 8;
  if (i >= n) return;
  float4 a = *reinterpret_cast<const float4*>(in + i);
  float4 b = *reinterpret_cast<const float4*>(in + i + 4);
  short8 r;
  r[0] = bf16b(a.x); r[1] = bf16b(a.y); r[2] = bf16b(a.z); r[3] = bf16b(a.w);
  r[4] = bf16b(b.x); r[5] = bf16b(b.y); r[6] = bf16b(b.z); r[7] = bf16b(b.w);
  *reinterpret_cast<short8*>(out + i) = r;
}

// ---------------------------------------------------------------------------
// transpose + convert: in [R][Cc] fp32 -> out [Cc][R] bf16
// ---------------------------------------------------------------------------
__global__ __launch_bounds__(256) void cvt_t(const float* __restrict__ in,
                                             short* __restrict__ out, int R, int Cc) {
  __shared__ float t[32][33];
  int c0 = blockIdx.x * 32, r0 = blockIdx.y * 32;
  int tx = threadIdx.x & 31, ty = threadIdx.x >> 5;
#pragma unroll
  for (int i = 0; i < 4; ++i)
    t[ty + i * 8][tx] = in[(size_t)(r0 + ty + i * 8) * Cc + c0 + tx];
  __syncthreads();
#pragma unroll
  for (int i = 0; i < 4; ++i)
    out[(size_t)(c0 + ty + i * 8) * R + r0 + tx] = bf16b(t[tx][ty + i * 8]);
}

// ---------------------------------------------------------------------------
// amask [B,T] ints -> per-64-key-tile u64 bitmasks kmask[B*32]
// ---------------------------------------------------------------------------
__global__ __launch_bounds__(256) void mask_pack(const int* __restrict__ amask,
                                                 unsigned long long* __restrict__ kmask) {
  const int gw = blockIdx.x * 4 + (threadIdx.x >> 6);
  const int lane = threadIdx.x & 63;
  unsigned long long bits = __ballot(amask[gw * 64 + lane] != 0);
  if (lane == 0) kmask[gw] = bits;
}

// ---------------------------------------------------------------------------
// V transpose + key-permute: qkv V-part -> vT[bh][d][t'] (perm within 32-key
// windows so PV A-frag key slots line up with swapped-QK^T lane ownership).
// ---------------------------------------------------------------------------
__global__ __launch_bounds__(256) void vtrans(const short* __restrict__ qkv,
                                              short* __restrict__ vT) {
  __shared__ short tile[64][72];
  const int bh = blockIdx.y, b = bh >> 4, h = bh & 15;
  const int t0 = blockIdx.x * 64;
  const int tr = threadIdx.x >> 2, dc = (threadIdx.x & 3) * 16;
  const short* src = qkv + (size_t)(b * TT + t0 + tr) * C3 + 2 * CC + h * 64 + dc;
  *reinterpret_cast<short8*>(&tile[tr][dc]) = *reinterpret_cast<const short8*>(src);
  *reinterpret_cast<short8*>(&tile[tr][dc + 8]) = *reinterpret_cast<const short8*>(src + 8);
  __syncthreads();
  const int d = threadIdx.x >> 2, p0 = (threadIdx.x & 3) * 16;
  short8 o1, o2;
#pragma unroll
  for (int i = 0; i < 8; ++i) {
    int p = p0 + i;
    int tl = (p & 32) | (((p >> 2) & 1) << 4) | (((p >> 3) & 3) << 2) | (p & 3);
    o1[i] = tile[tl][d];
    p = p0 + 8 + i;
    tl = (p & 32) | (((p >> 2) & 1) << 4) | (((p >> 3) & 3) << 2) | (p & 3);
    o2[i] = tile[tl][d];
  }
  short* dst = vT + (size_t)(bh * 64 + d) * TT + t0 + p0;
  *reinterpret_cast<short8*>(dst) = o1;
  *reinterpret_cast<short8*>(dst + 8) = o2;
}

// ---------------------------------------------------------------------------
// bf16 MFMA GEMM: C[M,N] = A[M,K] * Bt[N,K]^T.  128x128 tile, BK=32,
// 256 threads = 4 waves (2x2), 4x4 16x16 frags/wave, global_load_lds staging.
// ---------------------------------------------------------------------------
template <int OUT_BF16>
__global__ __launch_bounds__(256) void gemm_bt(const short* __restrict__ A,
                                               const short* __restrict__ Bt,
                                               void* __restrict__ Cout,
                                               int M, int N, int K) {
  __shared__ __align__(16) short As[128 * 32];
  __shared__ __align__(16) short Bs[128 * 32];
  const int tid = threadIdx.x, lane = tid & 63, w = tid >> 6;
  const int g = lane >> 4, cw = lane & 15;
  const int m0 = blockIdx.y * 128, n0 = blockIdx.x * 128;
  const int wr = (w >> 1) * 64, wc = (w & 1) * 64;

  f32x4 acc[4][4];
#pragma unroll
  for (int i = 0; i < 4; ++i)
#pragma unroll
    for (int j = 0; j < 4; ++j) acc[i][j] = (f32x4){0.f, 0.f, 0.f, 0.f};

  const int srow = w * 16 + (lane >> 2);  // + u*64
  const int scol = (lane & 3) * 8;        // k elements

  for (int k0 = 0; k0 < K; k0 += 32) {
    __syncthreads();
#pragma unroll
    for (int u = 0; u < 2; ++u) {
      gload16(A + (size_t)(m0 + srow + u * 64) * K + k0 + scol,
              (char*)As + u * 4096 + w * 1024);
      gload16(Bt + (size_t)(n0 + srow + u * 64) * K + k0 + scol,
              (char*)Bs + u * 4096 + w * 1024);
    }
    __syncthreads();
    short8 af[4], bf[4];
#pragma unroll
    for (int mt = 0; mt < 4; ++mt)
      af[mt] = *reinterpret_cast<const short8*>(&As[(wr + mt * 16 + cw) * 32 + g * 8]);
#pragma unroll
    for (int nt = 0; nt < 4; ++nt)
      bf[nt] = *reinterpret_cast<const short8*>(&Bs[(wc + nt * 16 + cw) * 32 + g * 8]);
#pragma unroll
    for (int mt = 0; mt < 4; ++mt)
#pragma unroll
      for (int nt = 0; nt < 4; ++nt)
        acc[mt][nt] = __builtin_amdgcn_mfma_f32_16x16x32_bf16(af[mt], bf[nt], acc[mt][nt], 0, 0, 0);
  }

#pragma unroll
  for (int mt = 0; mt < 4; ++mt)
#pragma unroll
    for (int nt = 0; nt < 4; ++nt)
#pragma unroll
      for (int j = 0; j < 4; ++j) {
        int row = m0 + wr + mt * 16 + g * 4 + j;
        int col = n0 + wc + nt * 16 + cw;
        if (OUT_BF16)
          ((short*)Cout)[(size_t)row * N + col] = bf16b(acc[mt][nt][j]);
        else
          ((float*)Cout)[(size_t)row * N + col] = acc[mt][nt][j];
      }
}

// ---------------------------------------------------------------------------
// Flash attention, swapped-operand MFMA, 8 waves (512 thr), q-tile 128,
// wave owns 16 q rows.  KV-tile 64, double-buffered LDS with counted vmcnt
// + raw s_barrier (loads stay in flight across barriers).  Causal pairing:
// blockIdx.x=i handles q-tiles {i, 15-i}.  Softmax lane-local (swapped QK^T),
// FMA-fused scale in exp2 domain, defer-max, P->A-frags via cvt_pk.
// ---------------------------------------------------------------------------
__global__ __launch_bounds__(512, 4) void attn_mfma(const short* __restrict__ qkv,
                                                    const short* __restrict__ vT,
                                                    const unsigned long long* __restrict__ kmask,
                                                    short* __restrict__ y) {
  __shared__ __align__(16) char Ks[2 * 8192];   // [buf][key][128B], swizzled
  __shared__ __align__(16) char Vs[2 * 8192];   // [buf][d][128B perm-keys], swizzled
  __shared__ unsigned long long km[32];
  const int tid = threadIdx.x, lane = tid & 63, w = tid >> 6;   // w: 0..7
  const int g = lane >> 4, cw = lane & 15;
  const int bh = blockIdx.y, b = bh >> 4, h = bh & 15;
  const int xorm = (cw & 7) << 4;
  const int srow = tid >> 3;                                // staging row 0..63
  const int scb = (((tid & 7) ^ ((tid >> 3) & 7)) << 4);    // pre-swizzled src col byte
  const float SC = 0.1803368801f;                           // log2(e)/8

  if (tid < 32) km[tid] = kmask[b * 32 + tid];
  __syncthreads();

  const char* ksrc = (const char*)qkv + ((size_t)(b * TT + srow) * C3 + CC + h * 64) * 2 + scb;
  const char* vsrc = (const char*)vT + ((size_t)(bh * 64 + srow) * TT) * 2 + scb;

#pragma unroll 1
  for (int part = 0; part < 2; ++part) {
    const int qt = part ? 15 - (int)blockIdx.x : (int)blockIdx.x;
    const int q0 = qt * 128;
    const int qw = q0 + w * 16;

    // Q fragments (B-operand: lane holds Q[q = qw+cw][d contiguous])
    short8 qf[2];
#pragma unroll
    for (int ks = 0; ks < 2; ++ks)
      qf[ks] = *reinterpret_cast<const short8*>(
          &qkv[(size_t)(b * TT + qw + cw) * C3 + h * 64 + ks * 32 + g * 8]);

    f32x4 o[4];
#pragma unroll
    for (int nd = 0; nd < 4; ++nd) o[nd] = (f32x4){0.f, 0.f, 0.f, 0.f};
    float mx = -1e30f, ls = 0.f;

    const int ntiles = 2 * qt + 2;
    // prologue: stage tile 0 into buf 0
    gload16(ksrc, Ks + tid * 16);
    gload16(vsrc, Vs + tid * 16);

#pragma unroll 1
    for (int t = 0; t < ntiles; ++t) {
      const int cur = t & 1;
      if (t + 1 < ntiles) {
        gload16(ksrc + (size_t)(t + 1) * (64 * C3 * 2), Ks + (cur ^ 1) * 8192 + tid * 16);
        gload16(vsrc + (size_t)(t + 1) * 128, Vs + (cur ^ 1) * 8192 + tid * 16);
        asm volatile("s_waitcnt vmcnt(2)" ::: "memory");
      } else {
        asm volatile("s_waitcnt vmcnt(0)" ::: "memory");
      }
      asm volatile("s_barrier" ::: "memory");

      if (t * 64 <= qw + 15) {
        const char* KB = Ks + cur * 8192;
        const char* VB = Vs + cur * 8192;

        // ---- S^T = K Q^T : lane holds q = cw, keys nt*16 + g*4 + j ----
        f32x4 s[4];
#pragma unroll
        for (int nt = 0; nt < 4; ++nt) {
          const int r = nt * 16 + cw;
          short8 kf0 = *reinterpret_cast<const short8*>(KB + r * 128 + ((g * 16) ^ xorm));
          short8 kf1 = *reinterpret_cast<const short8*>(KB + r * 128 + ((64 + g * 16) ^ xorm));
          f32x4 z = (f32x4){0.f, 0.f, 0.f, 0.f};
          s[nt] = __builtin_amdgcn_mfma_f32_16x16x32_bf16(kf0, qf[0], z, 0, 0, 0);
          s[nt] = __builtin_amdgcn_mfma_f32_16x16x32_bf16(kf1, qf[1], s[nt], 0, 0, 0);
        }

        // ---- mask (boundary tiles only) ----
        const unsigned long long kb = km[t];
        const bool needMask = (t * 64 + 63 > qw) || (kb != ~0ULL);
        if (needMask) {
          const int q = qw + cw;
#pragma unroll
          for (int nt = 0; nt < 4; ++nt)
#pragma unroll
            for (int j = 0; j < 4; ++j) {
              const int kh = nt * 16 + g * 4 + j;
              const bool mok = (kb >> kh) & 1;
              if (!(mok && t * 64 + kh <= q)) s[nt][j] = -1e30f;
            }
        }

        // ---- online softmax, defer-max, fused scale (exp2 domain) ----
        float vmax = s[0][0];
#pragma unroll
        for (int nt = 0; nt < 4; ++nt)
#pragma unroll
          for (int j = 0; j < 4; ++j) vmax = fmaxf(vmax, s[nt][j]);
        vmax = fmaxf(vmax, __shfl_xor(vmax, 16));
        vmax = fmaxf(vmax, __shfl_xor(vmax, 32));
        const float sm = vmax * SC;
        if (!__all(sm <= mx + 12.f)) {
          const float mn = fmaxf(mx, sm);
          const float al = exp2f(mx - mn);
          mx = mn;
          ls *= al;
#pragma unroll
          for (int j = 0; j < 4; ++j) {
            const float aj = __shfl(al, (lane & 48) | (g * 4 + j));
#pragma unroll
            for (int nd = 0; nd < 4; ++nd) o[nd][j] *= aj;
          }
        }
        float rs = 0.f;
#pragma unroll
        for (int nt = 0; nt < 4; ++nt)
#pragma unroll
          for (int j = 0; j < 4; ++j) {
            const float p = exp2f(fmaf(s[nt][j], SC, -mx));
            s[nt][j] = p;
            rs += p;
          }
        rs += __shfl_xor(rs, 16);
        rs += __shfl_xor(rs, 32);
        ls += rs;

        // ---- pack P into PV A-frags ----
        short8 pa[2];
#pragma unroll
        for (int ks2 = 0; ks2 < 2; ++ks2) {
          union { unsigned u[4]; short8 s8; } pc;
          pc.u[0] = cvtpk(s[2 * ks2][0], s[2 * ks2][1]);
          pc.u[1] = cvtpk(s[2 * ks2][2], s[2 * ks2][3]);
          pc.u[2] = cvtpk(s[2 * ks2 + 1][0], s[2 * ks2 + 1][1]);
          pc.u[3] = cvtpk(s[2 * ks2 + 1][2], s[2 * ks2 + 1][3]);
          pa[ks2] = pc.s8;
        }

        // ---- O += P V ----
#pragma unroll
        for (int ks2 = 0; ks2 < 2; ++ks2)
#pragma unroll
          for (int nd = 0; nd < 4; ++nd) {
            const int r = nd * 16 + cw;
            short8 vf = *reinterpret_cast<const short8*>(
                VB + r * 128 + ((ks2 * 64 + g * 16) ^ xorm));
            o[nd] = __builtin_amdgcn_mfma_f32_16x16x32_bf16(pa[ks2], vf, o[nd], 0, 0, 0);
          }
      }
      asm volatile("s_barrier" ::: "memory");
    }

    // ---- epilogue: y = O / l ----
#pragma unroll
    for (int j = 0; j < 4; ++j) {
      const float lj = __shfl(ls, (lane & 48) | (g * 4 + j));
      const float inv = 1.f / lj;
      const int q = qw + g * 4 + j;
#pragma unroll
      for (int nd = 0; nd < 4; ++nd)
        y[(size_t)(b * TT + q) * CC + h * 64 + nd * 16 + cw] = bf16b(o[nd][j] * inv);
    }
  }
}

// ---------------------------------------------------------------------------
extern "C" void kernel_launch(void* const* d_in, const int* in_sizes, int n_in,
                              void* d_out, int out_size, void* d_ws, size_t ws_size,
                              hipStream_t stream) {
  const float* x      = (const float*)d_in[0];
  const int*   amask  = (const int*)d_in[1];
  const float* W_attn = (const float*)d_in[2];
  const float* W_proj = (const float*)d_in[3];

  char* ws = (char*)d_ws;
  short* xb  = (short*)(ws);                    // [8192][1024] bf16   16.8 MB
  short* Wta = (short*)(ws + 16777216);         // [3072][1024] bf16    6.3 MB
  short* Wtp = (short*)(ws + 23068672);         // [1024][1024] bf16    2.1 MB
  short* qkv = (short*)(ws + 25165824);         // [8192][3072] bf16   50.3 MB
  short* y   = (short*)(ws + 75497472);         // [8192][1024] bf16   16.8 MB
  short* vT  = (short*)(ws + 92274688);         // [64bh][64d][2048t]  16.8 MB
  unsigned long long* kmask = (unsigned long long*)(ws + 109051904);  // 128 u64

  cvt_x<<<MM * CC / (256 * 8), 256, 0, stream>>>(x, xb, MM * CC);
  {
    dim3 g(C3 / 32, CC / 32);
    cvt_t<<<g, 256, 0, stream>>>(W_attn, Wta, CC, C3);
  }
  {
    dim3 g(CC / 32, CC / 32);
    cvt_t<<<g, 256, 0, stream>>>(W_proj, Wtp, CC, CC);
  }
  mask_pack<<<32, 256, 0, stream>>>(amask, kmask);
  {
    dim3 g(C3 / 128, MM / 128);
    gemm_bt<1><<<g, 256, 0, stream>>>(xb, Wta, qkv, MM, C3, CC);
  }
  {
    dim3 g(TT / 64, 64);
    vtrans<<<g, 256, 0, stream>>>(qkv, vT);
  }
  {
    dim3 g(8, 64);
    attn_mfma<<<g, 512, 0, stream>>>(qkv, vT, kmask, y);
  }
  {
    dim3 g(CC / 128, MM / 128);
    gemm_bt<0><<<g, 256, 0, stream>>>(y, Wtp, (void*)d_out, MM, CC, CC);
  }
}